// Round 1
// baseline (613.799 us; speedup 1.0000x reference)
//
#include <hip/hip_runtime.h>
#include <math.h>

#define N_ROWS 32768
#define K_CODES 8192
#define DIM 64
#define TM 64
#define TK 64

// ---------------- ws layout ----------------
// [0 .. 8191]        float w2g[8192]          (offset 0)
// [8192 .. 16383]    int   counts[8192]       (byte offset 32768)
// [16384]            float csum               (byte offset 65536)
#define WS_W2_OFF     0
#define WS_COUNTS_OFF (K_CODES * 4)
#define WS_CSUM_OFF   (K_CODES * 8)

// ---------------- kernel 1: w2[k] = sum_i W[k][i]^2 ----------------
__global__ __launch_bounds__(256) void vq_w2(const float* __restrict__ W,
                                             float* __restrict__ w2g) {
    int code = blockIdx.x * 4 + (threadIdx.x >> 6);
    int lane = threadIdx.x & 63;
    float v = W[(size_t)code * DIM + lane];
    float s = v * v;
    #pragma unroll
    for (int off = 32; off; off >>= 1) s += __shfl_down(s, off);
    if (lane == 0) w2g[code] = s;
}

// ---------------- kernel 2: main argmin + gather + partial losses ----------------
__global__ __launch_bounds__(256) void vq_main(const float* __restrict__ x,
                                               const float* __restrict__ W,
                                               const float* __restrict__ w2g,
                                               float* __restrict__ zout,
                                               int* __restrict__ counts,
                                               float* __restrict__ csum) {
    __shared__ __align__(16) float xT[DIM][TM + 4];  // [i][row], stride 68 floats
    __shared__ __align__(16) float wT[DIM][TK + 4];  // [i][code]
    __shared__ float w2s[TK];
    __shared__ float redv[TM][16];
    __shared__ int   redi[TM][16];
    __shared__ int   rowIdx[TM];

    const int t   = threadIdx.x;
    const int rq  = t >> 4;   // 0..15: row quad
    const int cq  = t & 15;   // 0..15: code quad
    const int row0 = blockIdx.x * TM;

    // stage x tile transposed (once per block)
    for (int f = t; f < TM * DIM / 4; f += 256) {
        int r  = f >> 4;
        int i4 = f & 15;
        float4 v = *(const float4*)(x + (size_t)(row0 + r) * DIM + i4 * 4);
        xT[i4 * 4 + 0][r] = v.x;
        xT[i4 * 4 + 1][r] = v.y;
        xT[i4 * 4 + 2][r] = v.z;
        xT[i4 * 4 + 3][r] = v.w;
    }

    float best[4];
    int   bidx[4];
    #pragma unroll
    for (int r = 0; r < 4; ++r) { best[r] = 3.4e38f; bidx[r] = 0; }

    for (int tile = 0; tile < K_CODES / TK; ++tile) {
        const int c0 = tile * TK;
        __syncthreads();  // protect wT from previous iteration's readers
        // stage W tile transposed
        for (int f = t; f < TK * DIM / 4; f += 256) {
            int c  = f >> 4;
            int i4 = f & 15;
            float4 v = *(const float4*)(W + (size_t)(c0 + c) * DIM + i4 * 4);
            wT[i4 * 4 + 0][c] = v.x;
            wT[i4 * 4 + 1][c] = v.y;
            wT[i4 * 4 + 2][c] = v.z;
            wT[i4 * 4 + 3][c] = v.w;
        }
        if (t < TK) w2s[t] = w2g[c0 + t];
        __syncthreads();

        float acc[4][4];
        #pragma unroll
        for (int r = 0; r < 4; ++r)
            #pragma unroll
            for (int c = 0; c < 4; ++c) acc[r][c] = 0.f;

        #pragma unroll 16
        for (int i = 0; i < DIM; ++i) {
            float4 xv = *(const float4*)&xT[i][rq * 4];
            float4 wv = *(const float4*)&wT[i][cq * 4];
            acc[0][0] += xv.x * wv.x; acc[0][1] += xv.x * wv.y; acc[0][2] += xv.x * wv.z; acc[0][3] += xv.x * wv.w;
            acc[1][0] += xv.y * wv.x; acc[1][1] += xv.y * wv.y; acc[1][2] += xv.y * wv.z; acc[1][3] += xv.y * wv.w;
            acc[2][0] += xv.z * wv.x; acc[2][1] += xv.z * wv.y; acc[2][2] += xv.z * wv.z; acc[2][3] += xv.z * wv.w;
            acc[3][0] += xv.w * wv.x; acc[3][1] += xv.w * wv.y; acc[3][2] += xv.w * wv.z; acc[3][3] += xv.w * wv.w;
        }

        // score = w2 - 2*dot  (x2 omitted: constant per row, argmin-invariant)
        #pragma unroll
        for (int c = 0; c < 4; ++c) {
            float w2  = w2s[cq * 4 + c];
            int   idx = c0 + cq * 4 + c;
            #pragma unroll
            for (int r = 0; r < 4; ++r) {
                float s = fmaf(-2.f, acc[r][c], w2);
                if (s < best[r] || (s == best[r] && idx < bidx[r])) { best[r] = s; bidx[r] = idx; }
            }
        }
    }

    // cross-thread reduce: 16 threads (same rq) share 4 rows
    #pragma unroll
    for (int r = 0; r < 4; ++r) { redv[rq * 4 + r][cq] = best[r]; redi[rq * 4 + r][cq] = bidx[r]; }
    __syncthreads();
    if (t < TM) {
        float bv = redv[t][0];
        int   bi = redi[t][0];
        #pragma unroll
        for (int j = 1; j < 16; ++j) {
            float v  = redv[t][j];
            int   i2 = redi[t][j];
            if (v < bv || (v == bv && i2 < bi)) { bv = v; bi = i2; }
        }
        rowIdx[t] = bi;
        atomicAdd(&counts[bi], 1);
    }
    __syncthreads();

    // z gather + commitment partial: thread -> (row = t>>2, 16-float segment = t&3)
    {
        int r   = t >> 2;
        int seg = t & 3;
        int idx = rowIdx[r];
        const float* wrow = W    + (size_t)idx * DIM + seg * 16;
        const float* xrow = x    + (size_t)(row0 + r) * DIM + seg * 16;
        float*       zrow = zout + (size_t)(row0 + r) * DIM + seg * 16;
        float local = 0.f;
        #pragma unroll
        for (int j = 0; j < 16; j += 4) {
            float4 wv = *(const float4*)(wrow + j);
            float4 xv = *(const float4*)(xrow + j);
            *(float4*)(zrow + j) = wv;
            float dx = wv.x - xv.x, dy = wv.y - xv.y, dz = wv.z - xv.z, dw = wv.w - xv.w;
            local += dx * dx + dy * dy + dz * dz + dw * dw;
        }
        #pragma unroll
        for (int off = 32; off; off >>= 1) local += __shfl_down(local, off);
        if ((t & 63) == 0) atomicAdd(csum, local);
    }
}

// ---------------- kernel 3: finalize scalars ----------------
__global__ __launch_bounds__(256) void vq_final(const int* __restrict__ counts,
                                                const float* __restrict__ csum,
                                                float* __restrict__ out3) {
    __shared__ float sh[4];
    float e = 0.f;
    for (int i = threadIdx.x; i < K_CODES; i += 256) {
        float p = (float)counts[i] * (1.0f / N_ROWS);
        e += p * logf(p + 1e-10f);
    }
    #pragma unroll
    for (int off = 32; off; off >>= 1) e += __shfl_down(e, off);
    if ((threadIdx.x & 63) == 0) sh[threadIdx.x >> 6] = e;
    __syncthreads();
    if (threadIdx.x == 0) {
        float tot = sh[0] + sh[1] + sh[2] + sh[3];
        out3[0] = 0.f;                                        // codebook_loss
        out3[1] = csum[0] * (1.0f / ((float)N_ROWS * DIM));   // commitment_loss
        out3[2] = expf(-tot);                                 // perplexity
    }
}

extern "C" void kernel_launch(void* const* d_in, const int* in_sizes, int n_in,
                              void* d_out, int out_size, void* d_ws, size_t ws_size,
                              hipStream_t stream) {
    (void)in_sizes; (void)n_in; (void)out_size; (void)ws_size;
    const float* x = (const float*)d_in[0];
    const float* W = (const float*)d_in[1];
    float* zout = (float*)d_out;
    float* out3 = (float*)d_out + (size_t)N_ROWS * DIM;

    float* w2g    = (float*)((char*)d_ws + WS_W2_OFF);
    int*   counts = (int*)  ((char*)d_ws + WS_COUNTS_OFF);
    float* csum   = (float*)((char*)d_ws + WS_CSUM_OFF);

    // zero counts + csum (capture-legal async memset)
    hipMemsetAsync((char*)d_ws + WS_COUNTS_OFF, 0, K_CODES * 4 + 4, stream);

    vq_w2<<<K_CODES / 4, 256, 0, stream>>>(W, w2g);
    vq_main<<<N_ROWS / TM, 256, 0, stream>>>(x, W, w2g, zout, counts, csum);
    vq_final<<<1, 256, 0, stream>>>(counts, csum, out3);
}

// Round 2
// 296.015 us; speedup vs baseline: 2.0735x; 2.0735x over previous
//
#include <hip/hip_runtime.h>
#include <math.h>

#define N_ROWS 32768
#define K_CODES 8192
#define DIM 64

using half8  = __attribute__((ext_vector_type(8))) _Float16;
using f32x16 = __attribute__((ext_vector_type(16))) float;

// ---------------- ws layout ----------------
// [0]        float w2g[8192]                 32 KB
// [32768]    int   counts[8192]              32 KB
// [65536]    float csum (+pad)               16 B
// [65552]    u64   best[32768]               256 KB
// [327936]   _Float16 whl[8192][128]         2 MB   (hi[64] | lo[64] per code)
#define WS_W2     0
#define WS_COUNTS 32768
#define WS_CSUM   65536
#define WS_BEST   65552
#define WS_WHL    327936

// ---------------- kernel 1: w2[k] = sum_i W[k][i]^2 (fp32 exact-ish) ----------------
__global__ __launch_bounds__(256) void vq_w2(const float* __restrict__ W,
                                             float* __restrict__ w2g) {
    int code = blockIdx.x * 4 + (threadIdx.x >> 6);
    int lane = threadIdx.x & 63;
    float v = W[(size_t)code * DIM + lane];
    float s = v * v;
    #pragma unroll
    for (int off = 32; off; off >>= 1) s += __shfl_down(s, off);
    if (lane == 0) w2g[code] = s;
}

// ---------------- kernel 2: split W into f16 hi/lo ----------------
__global__ __launch_bounds__(256) void vq_prep(const float* __restrict__ W,
                                               _Float16* __restrict__ whl) {
    int g = blockIdx.x * 256 + threadIdx.x;   // 0 .. 524287
    int code = g >> 6, k = g & 63;
    float w = W[g];
    _Float16 h = (_Float16)w;
    _Float16 l = (_Float16)(w - (float)h);
    whl[(size_t)code * 128 + k]      = h;
    whl[(size_t)code * 128 + 64 + k] = l;
}

// ---------------- kernel 3: MFMA scores + per-row argmin ----------------
// block = 256 thr = 4 waves. wave w: rows rblk*128 + w*32 .. +31, codes chunk*2048 .. +2047.
// A (x rows) in registers; B (codes) read from whl via L1/L2; no LDS.
__global__ __launch_bounds__(256, 4) void vq_mfma(const float* __restrict__ x,
                                                  const _Float16* __restrict__ whl,
                                                  const float* __restrict__ w2g,
                                                  unsigned long long* __restrict__ best) {
    const int t     = threadIdx.x;
    const int wv    = t >> 6;
    const int l     = t & 63;
    const int ln31  = l & 31;
    const int lhalf = l >> 5;            // 0/1: which K-half this lane holds
    const int chunk = blockIdx.x & 3;
    const int rblk  = blockIdx.x >> 2;
    const int rowb  = rblk * 128 + wv * 32;
    const int row   = rowb + ln31;

    // ---- load x row, exact f16 hi/lo split: lane holds k = kt*16 + lhalf*8 + j ----
    half8 ahi[4], alo[4];
    {
        const float* xr = x + (size_t)row * DIM + lhalf * 8;
        #pragma unroll
        for (int kt = 0; kt < 4; ++kt) {
            float4 v0 = *(const float4*)(xr + kt * 16);
            float4 v1 = *(const float4*)(xr + kt * 16 + 4);
            float f[8] = {v0.x, v0.y, v0.z, v0.w, v1.x, v1.y, v1.z, v1.w};
            #pragma unroll
            for (int j = 0; j < 8; ++j) {
                _Float16 h = (_Float16)f[j];
                ahi[kt][j] = h;
                alo[kt][j] = (_Float16)(f[j] - (float)h);
            }
        }
    }

    float bv[16];
    int   bi[16];
    #pragma unroll
    for (int s = 0; s < 16; ++s) { bv[s] = 3.4e38f; bi[s] = 0; }

    const int cbase = chunk * 2048;
    // per-lane B pointer: code = cbase + tile*32 + ln31, k-slice = lhalf*8
    const _Float16* wp = whl + (size_t)(cbase + ln31) * 128 + lhalf * 8;

    for (int tile = 0; tile < 64; ++tile) {
        f32x16 acc = {};
        #pragma unroll
        for (int kt = 0; kt < 4; ++kt) {
            half8 bh = *(const half8*)(wp + kt * 16);        // hi block
            half8 bl = *(const half8*)(wp + 64 + kt * 16);   // lo block
            acc = __builtin_amdgcn_mfma_f32_32x32x16_f16(ahi[kt], bh, acc, 0, 0, 0);
            acc = __builtin_amdgcn_mfma_f32_32x32x16_f16(ahi[kt], bl, acc, 0, 0, 0);
            acc = __builtin_amdgcn_mfma_f32_32x32x16_f16(alo[kt], bh, acc, 0, 0, 0);
        }
        const int   c   = cbase + tile * 32 + ln31;   // this lane's code (C col = lane&31)
        const float w2v = w2g[c];
        #pragma unroll
        for (int s = 0; s < 16; ++s) {
            float sc = fmaf(-2.f, acc[s], w2v);
            if (sc < bv[s]) { bv[s] = sc; bi[s] = c; }   // strict <: earlier (smaller) idx wins ties
        }
        wp += 32 * 128;
    }

    // ---- per-row reduce across the 32 lanes sharing that row, then global merge ----
    #pragma unroll
    for (int s = 0; s < 16; ++s) {
        unsigned uk = __float_as_uint(bv[s]);
        uk = (uk >> 31) ? ~uk : (uk | 0x80000000u);      // monotone float->uint
        unsigned long long key = ((unsigned long long)uk << 32) | (unsigned)bi[s];
        #pragma unroll
        for (int off = 16; off; off >>= 1) {
            unsigned long long o = __shfl_xor(key, off); // stays within each 32-lane half
            key = (o < key) ? o : key;
        }
        if (ln31 == 0) {
            int rl = (s & 3) + 8 * (s >> 2) + 4 * lhalf; // C row mapping (m74/m101)
            atomicMin(&best[rowb + rl], key);
        }
    }
}

// ---------------- kernel 4: gather z, commitment partial, histogram ----------------
__global__ __launch_bounds__(256) void vq_gather(const float* __restrict__ x,
                                                 const float* __restrict__ W,
                                                 const unsigned long long* __restrict__ best,
                                                 float* __restrict__ zout,
                                                 int* __restrict__ counts,
                                                 float* __restrict__ csum) {
    int t   = threadIdx.x;
    int row = blockIdx.x * 64 + (t >> 2);
    int seg = t & 3;
    int idx = (int)(best[row] & 0xFFFFFFFFULL);
    if (seg == 0) atomicAdd(&counts[idx], 1);
    const float* wrow = W    + (size_t)idx * DIM + seg * 16;
    const float* xrow = x    + (size_t)row * DIM + seg * 16;
    float*       zrow = zout + (size_t)row * DIM + seg * 16;
    float local = 0.f;
    #pragma unroll
    for (int j = 0; j < 16; j += 4) {
        float4 wv = *(const float4*)(wrow + j);
        float4 xv = *(const float4*)(xrow + j);
        *(float4*)(zrow + j) = wv;
        float dx = wv.x - xv.x, dy = wv.y - xv.y, dz = wv.z - xv.z, dw = wv.w - xv.w;
        local += dx * dx + dy * dy + dz * dz + dw * dw;
    }
    #pragma unroll
    for (int off = 32; off; off >>= 1) local += __shfl_down(local, off);
    if ((t & 63) == 0) atomicAdd(csum, local);
}

// ---------------- kernel 5: finalize scalars ----------------
__global__ __launch_bounds__(256) void vq_final(const int* __restrict__ counts,
                                                const float* __restrict__ csum,
                                                float* __restrict__ out3) {
    __shared__ float sh[4];
    float e = 0.f;
    for (int i = threadIdx.x; i < K_CODES; i += 256) {
        float p = (float)counts[i] * (1.0f / N_ROWS);
        e += p * logf(p + 1e-10f);
    }
    #pragma unroll
    for (int off = 32; off; off >>= 1) e += __shfl_down(e, off);
    if ((threadIdx.x & 63) == 0) sh[threadIdx.x >> 6] = e;
    __syncthreads();
    if (threadIdx.x == 0) {
        float tot = sh[0] + sh[1] + sh[2] + sh[3];
        out3[0] = 0.f;
        out3[1] = csum[0] * (1.0f / ((float)N_ROWS * DIM));
        out3[2] = expf(-tot);
    }
}

extern "C" void kernel_launch(void* const* d_in, const int* in_sizes, int n_in,
                              void* d_out, int out_size, void* d_ws, size_t ws_size,
                              hipStream_t stream) {
    (void)in_sizes; (void)n_in; (void)out_size; (void)ws_size;
    const float* x = (const float*)d_in[0];
    const float* W = (const float*)d_in[1];
    float* zout = (float*)d_out;
    float* out3 = (float*)d_out + (size_t)N_ROWS * DIM;

    float*              w2g    = (float*)((char*)d_ws + WS_W2);
    int*                counts = (int*)((char*)d_ws + WS_COUNTS);
    float*              csum   = (float*)((char*)d_ws + WS_CSUM);
    unsigned long long* best   = (unsigned long long*)((char*)d_ws + WS_BEST);
    _Float16*           whl    = (_Float16*)((char*)d_ws + WS_WHL);

    hipMemsetAsync((char*)d_ws + WS_COUNTS, 0,    K_CODES * 4 + 16, stream); // counts + csum
    hipMemsetAsync((char*)d_ws + WS_BEST,   0xFF, N_ROWS * 8,       stream); // best = +inf keys

    vq_w2  <<<K_CODES / 4,            256, 0, stream>>>(W, w2g);
    vq_prep<<<K_CODES * DIM / 256,    256, 0, stream>>>(W, whl);
    vq_mfma<<<(N_ROWS / 128) * 4,     256, 0, stream>>>(x, whl, w2g, best);
    vq_gather<<<N_ROWS / 64,          256, 0, stream>>>(x, W, best, zout, counts, csum);
    vq_final<<<1,                     256, 0, stream>>>(counts, csum, out3);
}

// Round 3
// 152.221 us; speedup vs baseline: 4.0323x; 1.9446x over previous
//
#include <hip/hip_runtime.h>
#include <math.h>

#define N_ROWS 32768
#define K_CODES 8192
#define DIM 64

using half8  = __attribute__((ext_vector_type(8))) _Float16;
using f32x16 = __attribute__((ext_vector_type(16))) float;

// ---------------- ws layout ----------------
#define WS_W2     0          // float w2g[8192]        32 KB
#define WS_COUNTS 32768      // int counts[8192]       32 KB
#define WS_CSUM   65536      // float csum             16 B
#define WS_BEST   65552      // u64 best[32768]        256 KB
#define WS_WHL    327936     // _Float16 whl[8192][128]  2 MB (hi[64]|lo[64])

__device__ __forceinline__ void gload_lds16(const _Float16* g, _Float16* l) {
    __builtin_amdgcn_global_load_lds(
        (const __attribute__((address_space(1))) void*)g,
        (__attribute__((address_space(3))) void*)l, 16, 0, 0);
}

// ---------------- kernel 1: fused w2 + f16 hi/lo split ----------------
// 64 lanes per code: lane k handles W[c][k]
__global__ __launch_bounds__(256) void vq_prep(const float* __restrict__ W,
                                               _Float16* __restrict__ whl,
                                               float* __restrict__ w2g) {
    int code = blockIdx.x * 4 + (threadIdx.x >> 6);
    int k    = threadIdx.x & 63;
    float w = W[(size_t)code * DIM + k];
    _Float16 h = (_Float16)w;
    _Float16 l = (_Float16)(w - (float)h);
    whl[(size_t)code * 128 + k]      = h;
    whl[(size_t)code * 128 + 64 + k] = l;
    float s = w * w;
    #pragma unroll
    for (int off = 32; off; off >>= 1) s += __shfl_down(s, off);
    if (k == 0) w2g[code] = s;
}

// ---------------- kernel 2: MFMA scores + per-row argmin ----------------
// block = 4 waves; wave handles 64 rows (2 groups of 32) x 2048-code chunk.
// B tile (32 codes x 128 halves = 8KB) LDS-staged fragment-major, double-buffered.
__global__ __launch_bounds__(256, 2) void vq_mfma(const float* __restrict__ x,
                                                  const _Float16* __restrict__ whl,
                                                  const float* __restrict__ w2g,
                                                  unsigned long long* __restrict__ best) {
    __shared__ _Float16 lds[2][4096];   // 2 x 8KB

    const int t     = threadIdx.x;
    const int wv    = t >> 6;
    const int l     = t & 63;
    const int ln31  = l & 31;
    const int lhalf = l >> 5;
    const int chunk = blockIdx.x & 3;
    const int rblk  = blockIdx.x >> 2;
    const int rowb  = rblk * 256 + wv * 64;      // wave's first row
    const int cbase = chunk * 2048;

    // ---- A fragments: 2 row-groups, exact f16 hi/lo split ----
    half8 ahi[2][4], alo[2][4];
    #pragma unroll
    for (int rg = 0; rg < 2; ++rg) {
        const float* xr = x + (size_t)(rowb + rg * 32 + ln31) * DIM + lhalf * 8;
        #pragma unroll
        for (int kt = 0; kt < 4; ++kt) {
            float4 v0 = *(const float4*)(xr + kt * 16);
            float4 v1 = *(const float4*)(xr + kt * 16 + 4);
            float f[8] = {v0.x, v0.y, v0.z, v0.w, v1.x, v1.y, v1.z, v1.w};
            #pragma unroll
            for (int j = 0; j < 8; ++j) {
                _Float16 h = (_Float16)f[j];
                ahi[rg][kt][j] = h;
                alo[rg][kt][j] = (_Float16)(f[j] - (float)h);
            }
        }
    }

    // ---- staging source for this thread's 2 granules (16B each) ----
    // G = p*256 + t ; ls=G&63 ; q=G>>6 ; kt=q>>1 ; hl=q&1
    // src granule: code = cbase + (ls&31), half-offset = (hl*8 + (ls>>5) + 2*kt)*8
    const _Float16* src[2];
    int ldsG[2];
    #pragma unroll
    for (int p = 0; p < 2; ++p) {
        int G  = p * 256 + t;
        int ls = G & 63, q = G >> 6, kt = q >> 1, hl = q & 1;
        src[p]  = whl + (size_t)(cbase + (ls & 31)) * 128 + (hl * 8 + (ls >> 5) + 2 * kt) * 8;
        ldsG[p] = (p * 256 + wv * 64) * 8;   // wave-uniform LDS base (halves); HW adds lane*16B
    }

    float bv[2][16];
    int   bi[2][16];
    #pragma unroll
    for (int rg = 0; rg < 2; ++rg)
        #pragma unroll
        for (int s = 0; s < 16; ++s) { bv[rg][s] = 3.4e38f; bi[rg][s] = 0; }

    // prologue: stage tile 0 into buf 0
    #pragma unroll
    for (int p = 0; p < 2; ++p) gload_lds16(src[p], &lds[0][ldsG[p]]);
    __syncthreads();

    const float* w2p = w2g + cbase + ln31;
    int cur = 0;

    for (int tile = 0; tile < 64; ++tile) {
        // prefetch next tile into buf^1 (codes advance by 32 -> +4096 halves)
        if (tile < 63) {
            #pragma unroll
            for (int p = 0; p < 2; ++p)
                gload_lds16(src[p] + (tile + 1) * 4096, &lds[cur ^ 1][ldsG[p]]);
        }
        const float w2v = w2p[tile * 32];

        f32x16 acc0 = {}, acc1 = {};
        #pragma unroll
        for (int kt = 0; kt < 4; ++kt) {
            half8 bh = *(const half8*)&lds[cur][((kt * 2 + 0) * 64 + l) * 8];
            half8 bl = *(const half8*)&lds[cur][((kt * 2 + 1) * 64 + l) * 8];
            acc0 = __builtin_amdgcn_mfma_f32_32x32x16_f16(ahi[0][kt], bh, acc0, 0, 0, 0);
            acc1 = __builtin_amdgcn_mfma_f32_32x32x16_f16(ahi[1][kt], bh, acc1, 0, 0, 0);
            acc0 = __builtin_amdgcn_mfma_f32_32x32x16_f16(alo[0][kt], bh, acc0, 0, 0, 0);
            acc1 = __builtin_amdgcn_mfma_f32_32x32x16_f16(alo[1][kt], bh, acc1, 0, 0, 0);
            acc0 = __builtin_amdgcn_mfma_f32_32x32x16_f16(ahi[0][kt], bl, acc0, 0, 0, 0);
            acc1 = __builtin_amdgcn_mfma_f32_32x32x16_f16(ahi[1][kt], bl, acc1, 0, 0, 0);
        }

        const int c = cbase + tile * 32 + ln31;
        #pragma unroll
        for (int s = 0; s < 16; ++s) {
            float s0 = fmaf(-2.f, acc0[s], w2v);
            float s1 = fmaf(-2.f, acc1[s], w2v);
            if (s0 < bv[0][s]) { bv[0][s] = s0; bi[0][s] = c; }
            if (s1 < bv[1][s]) { bv[1][s] = s1; bi[1][s] = c; }
        }
        __syncthreads();
        cur ^= 1;
    }

    // ---- per-row reduce across 32 lanes, then global merge ----
    #pragma unroll
    for (int rg = 0; rg < 2; ++rg) {
        #pragma unroll
        for (int s = 0; s < 16; ++s) {
            unsigned uk = __float_as_uint(bv[rg][s]);
            uk = (uk >> 31) ? ~uk : (uk | 0x80000000u);
            unsigned long long key = ((unsigned long long)uk << 32) | (unsigned)bi[rg][s];
            #pragma unroll
            for (int off = 16; off; off >>= 1) {
                unsigned long long o = __shfl_xor(key, off);
                key = (o < key) ? o : key;
            }
            if (ln31 == 0) {
                int rl = (s & 3) + 8 * (s >> 2) + 4 * lhalf;   // C/D row map (m74/m101)
                atomicMin(&best[rowb + rg * 32 + rl], key);
            }
        }
    }
}

// ---------------- kernel 3: gather z, commitment partial, histogram ----------------
__global__ __launch_bounds__(256) void vq_gather(const float* __restrict__ x,
                                                 const float* __restrict__ W,
                                                 const unsigned long long* __restrict__ best,
                                                 float* __restrict__ zout,
                                                 int* __restrict__ counts,
                                                 float* __restrict__ csum) {
    int t   = threadIdx.x;
    int row = blockIdx.x * 64 + (t >> 2);
    int seg = t & 3;
    int idx = (int)(best[row] & 0xFFFFFFFFULL);
    if (seg == 0) atomicAdd(&counts[idx], 1);
    const float* wrow = W    + (size_t)idx * DIM + seg * 16;
    const float* xrow = x    + (size_t)row * DIM + seg * 16;
    float*       zrow = zout + (size_t)row * DIM + seg * 16;
    float local = 0.f;
    #pragma unroll
    for (int j = 0; j < 16; j += 4) {
        float4 wv = *(const float4*)(wrow + j);
        float4 xv = *(const float4*)(xrow + j);
        *(float4*)(zrow + j) = wv;
        float dx = wv.x - xv.x, dy = wv.y - xv.y, dz = wv.z - xv.z, dw = wv.w - xv.w;
        local += dx * dx + dy * dy + dz * dz + dw * dw;
    }
    #pragma unroll
    for (int off = 32; off; off >>= 1) local += __shfl_down(local, off);
    if ((t & 63) == 0) atomicAdd(csum, local);
}

// ---------------- kernel 4: finalize scalars ----------------
__global__ __launch_bounds__(256) void vq_final(const int* __restrict__ counts,
                                                const float* __restrict__ csum,
                                                float* __restrict__ out3) {
    __shared__ float sh[4];
    float e = 0.f;
    for (int i = threadIdx.x; i < K_CODES; i += 256) {
        float p = (float)counts[i] * (1.0f / N_ROWS);
        e += p * logf(p + 1e-10f);
    }
    #pragma unroll
    for (int off = 32; off; off >>= 1) e += __shfl_down(e, off);
    if ((threadIdx.x & 63) == 0) sh[threadIdx.x >> 6] = e;
    __syncthreads();
    if (threadIdx.x == 0) {
        float tot = sh[0] + sh[1] + sh[2] + sh[3];
        out3[0] = 0.f;
        out3[1] = csum[0] * (1.0f / ((float)N_ROWS * DIM));
        out3[2] = expf(-tot);
    }
}

extern "C" void kernel_launch(void* const* d_in, const int* in_sizes, int n_in,
                              void* d_out, int out_size, void* d_ws, size_t ws_size,
                              hipStream_t stream) {
    (void)in_sizes; (void)n_in; (void)out_size; (void)ws_size;
    const float* x = (const float*)d_in[0];
    const float* W = (const float*)d_in[1];
    float* zout = (float*)d_out;
    float* out3 = (float*)d_out + (size_t)N_ROWS * DIM;

    float*              w2g    = (float*)((char*)d_ws + WS_W2);
    int*                counts = (int*)((char*)d_ws + WS_COUNTS);
    float*              csum   = (float*)((char*)d_ws + WS_CSUM);
    unsigned long long* best   = (unsigned long long*)((char*)d_ws + WS_BEST);
    _Float16*           whl    = (_Float16*)((char*)d_ws + WS_WHL);

    hipMemsetAsync((char*)d_ws + WS_COUNTS, 0,    K_CODES * 4 + 16, stream);
    hipMemsetAsync((char*)d_ws + WS_BEST,   0xFF, N_ROWS * 8,       stream);

    vq_prep  <<<K_CODES / 4,          256, 0, stream>>>(W, whl, w2g);
    vq_mfma  <<<(N_ROWS / 256) * 4,   256, 0, stream>>>(x, whl, w2g, best);
    vq_gather<<<N_ROWS / 64,          256, 0, stream>>>(x, W, best, zout, counts, csum);
    vq_final <<<1,                    256, 0, stream>>>(counts, csum, out3);
}